// Round 11
// baseline (83.611 us; speedup 1.0000x reference)
//
#include <hip/hip_runtime.h>

#define BB 128
#define NN 16384
#define CC 8
#define WW 10
#define LL 16375            // N - W + 1
#define NT 512              // n's per block tile
#define NTILES (NN / NT)    // 32
#define BT 8                // b's per k_fir block (one wave per b)
#define BTILES (BB / BT)    // 16
#define WSL (NT + 9)        // 521 staged taps
#define SWSZ (WSL * 4 + 17) // f4 slots incl. skew padding
#define BPB 2               // b per k_nonlin block
#define ABLK (BB / BPB)     // 64

typedef float f4_t __attribute__((ext_vector_type(4)));

// ---------------------------------------------------------------------------
// K1: FIR. Grid = BTILES*NTILES = 512 blocks x 512 threads (8 waves).
// Wave wvb owns batch b = bt*8+wvb for the whole 512-n tile: lane = (c2, s),
// s = 16 slices x 32 consecutive n. Taps staged once per block in LDS with a
// +(j>>5) skew. R6-proven 16-slot window loop via TAP() macro. Reduce over s
// fully in-wave (shfl_xor); lanes 0..39 store transposed to fpart2[r][b][nt].
// __launch_bounds__(512, 2): 2 waves/EU -> 256-VGPR cap. R10's plain (512)
// let the backend pick 64 VGPRs -> ~90 regs/thread spilled to scratch
// (WRITE_SIZE 164 MB, 100 us). Working set ~150 VGPRs needs the 256 tier.
// ---------------------------------------------------------------------------
__global__ __launch_bounds__(512, 2) void k_fir(const float* __restrict__ x,
                                                const float* __restrict__ wr,
                                                const float* __restrict__ wi,
                                                float* __restrict__ fpart2) {
  __shared__ f4_t sw[SWSZ];          // 33.6 KB
  int nt = blockIdx.x & (NTILES - 1);
  int bt = blockIdx.x >> 5;          // NTILES = 32
  int tid = threadIdx.x;
  int ntile = nt * NT;
  int l0 = ntile - 9;

  // ---- stage taps: sw[j*4 + c2 + (j>>5)] = {wr[2c2][l], wi[2c2][l], wr[2c2+1][l], wi[2c2+1][l]} ----
  {
    int c2s = tid & 3;
    int ca = 2 * c2s, cb = ca + 1;
    for (int j = tid >> 2; j < WSL; j += 128) {
      int l = l0 + j;
      f4_t v = (f4_t)0.f;
      if (l >= 0 && l < LL) {
        v[0] = wr[(size_t)ca * LL + l];
        v[1] = wi[(size_t)ca * LL + l];
        v[2] = wr[(size_t)cb * LL + l];
        v[3] = wi[(size_t)cb * LL + l];
      }
      sw[j * 4 + c2s + (j >> 5)] = v;
    }
  }
  __syncthreads();

  int wvb = tid >> 6;                // wave id = batch sub-index
  int b   = bt * BT + wvb;
  int c2  = tid & 3;
  int s   = (tid >> 2) & 15;         // 32-n slice
  int jbase = s * 32 + 9;            // tap j for local offset q: j = jbase + q

  const f4_t* __restrict__ xp = (const f4_t*)x + ((size_t)b * NN + ntile + s * 32) * 4 + c2;

#define TAP(q) sw[(jbase + (q)) * 4 + c2 + ((jbase + (q)) >> 5)]

  f4_t acc[WW];
#pragma unroll
  for (int w = 0; w < WW; ++w) acc[w] = (f4_t)0.f;

  f4_t wv[16];
  // preload slots 7..15 = taps q = -9..-1 (zero-padded in LDS)
#pragma unroll
  for (int k = 0; k < 9; ++k) wv[7 + k] = TAP(k - 9);

#pragma unroll
  for (int g = 0; g < 2; ++g) {
#pragma unroll
    for (int j = 0; j < 7; ++j) wv[j] = TAP(16 * g + j);
#pragma unroll
    for (int u = 0; u < 16; ++u) {
      f4_t xv = xp[(size_t)(16 * g + u) * 4];
#pragma unroll
      for (int w = 0; w < WW; ++w) {
        f4_t wt = wv[(u - w + 16) & 15];
        acc[w] += xv * wt;             // v_pk_fma_f32 x2
      }
      if (u <= 8) wv[u + 7] = TAP(16 * g + u + 7);   // refill after last use
    }
  }

  // ---- reduce over s (lane bits 2..5) fully in-wave ----
#pragma unroll
  for (int w = 0; w < WW; ++w)
#pragma unroll
    for (int e = 0; e < 4; ++e) {
      acc[w][e] += __shfl_xor(acc[w][e], 4);
      acc[w][e] += __shfl_xor(acc[w][e], 8);
      acc[w][e] += __shfl_xor(acc[w][e], 16);
      acc[w][e] += __shfl_xor(acc[w][e], 32);
    }

  // ---- store transposed: fpart2[(r*BB + b)*NTILES + nt], r = w*16 + c2*4 + e ----
  int lane = tid & 63;
  if (lane < 40) {
    int w = lane >> 2;                 // c2 = lane & 3 (matches compute c2)
#pragma unroll
    for (int e = 0; e < 4; ++e)
      fpart2[((size_t)(w * 16 + c2 * 4 + e) * BB + b) * NTILES + nt] = acc[w][e];
  }
}

// ---------------------------------------------------------------------------
// K2: nonlin + projection. Grid = 64 blocks x 256 threads. Dense gather:
// thread-iter (r, bl) reads 8 consecutive float4 of fpart2 and tile-reduces.
// ---------------------------------------------------------------------------
__global__ __launch_bounds__(256) void k_nonlin(const float* __restrict__ fpart2,
                                                const float* __restrict__ wc,
                                                const float* __restrict__ wor,
                                                const float* __restrict__ woi,
                                                float* __restrict__ oraw,
                                                float* __restrict__ part) {
  __shared__ float sred[BPB][164];
  __shared__ float swc[672];
  __shared__ float swout[160];       // [p][c][w]

  int tid = threadIdx.x;
  int blk = blockIdx.x;
  int b0 = blk * BPB;

  for (int i = tid; i < 672; i += 256) swc[i] = wc[i];
  if (tid < 80) swout[tid] = wor[tid];
  else if (tid < 160) swout[tid] = woi[tid - 80];

  // dense stage: r = row (0..159), bl = batch-in-block; 8 consecutive f4 each
  for (int t = tid; t < 2 * 160; t += 256) {
    int r = t >> 1, bl = t & 1;
    const f4_t* fp = (const f4_t*)(fpart2 + ((size_t)r * BB + b0 + bl) * NTILES);
    f4_t s4 = (f4_t)0.f;
#pragma unroll
    for (int k = 0; k < NTILES / 4; ++k) s4 += fp[k];
    sred[bl][r] = s4[0] + s4[1] + s4[2] + s4[3];
  }
  __syncthreads();

  if (tid < 32) {
    int bl = tid >> 4;
    int c  = (tid >> 1) & 7;
    int p  = tid & 1;

    float wreg[8][2][3];
#pragma unroll
    for (int j = 0; j < 8; ++j) {
      int jj = j - (j > c ? 1 : 0);
      if (j == c) jj = 0;
#pragma unroll
      for (int ri = 0; ri < 2; ++ri)
#pragma unroll
        for (int d = 0; d < 3; ++d) {
          float v = swc[(c * 2 + p) * 42 + ri * 21 + jj * 3 + d];
          wreg[j][ri][d] = (j == c) ? 0.f : v;
        }
    }

    float o = 0.f;
    const float* wop = swout + p * 80 + c * 10;
#pragma unroll
    for (int w = 0; w < WW; ++w) {
      float4 f0 = *(const float4*)&sred[bl][w * 16];
      float4 f1 = *(const float4*)&sred[bl][w * 16 + 4];
      float4 f2 = *(const float4*)&sred[bl][w * 16 + 8];
      float4 f3 = *(const float4*)&sred[bl][w * 16 + 12];
      float fv[16] = {f0.x, f0.y, f0.z, f0.w, f1.x, f1.y, f1.z, f1.w,
                      f2.x, f2.y, f2.z, f2.w, f3.x, f3.y, f3.z, f3.w};
      float nl0 = 0.f, nl1 = 0.f, nl2 = 0.f;
#pragma unroll
      for (int j = 0; j < 8; ++j) {
        float r  = fv[2 * j];
        float im = fv[2 * j + 1];
        float r2 = r * r, i2 = im * im;
        float pw0 = r + im;
        float pw1 = r2 + i2;
        float pw2 = r2 * r + i2 * im;
        nl0 += (pw0 * r) * wreg[j][0][0] + (pw0 * im) * wreg[j][1][0];
        nl1 += (pw1 * r) * wreg[j][0][1] + (pw1 * im) * wreg[j][1][1];
        nl2 += (pw2 * r) * wreg[j][0][2] + (pw2 * im) * wreg[j][1][2];
      }
      o += (nl0 + nl1 + nl2) * wop[w];
    }

    oraw[((size_t)(b0 + bl) * CC + c) * 2 + p] = o;

    float s = o, q = o * o;
    s += __shfl_xor(s, 1);  q += __shfl_xor(q, 1);
    s += __shfl_xor(s, 16); q += __shfl_xor(q, 16);
    if ((tid & 17) == 0) {             // p==0 && bl==0 -> tid = c*2
      part[blk * 16 + c * 2 + 0] = s;
      part[blk * 16 + c * 2 + 1] = q;
    }
  }
}

// ---------------------------------------------------------------------------
// K3: BatchNorm finalize. 1 block x 256 threads.
// ---------------------------------------------------------------------------
__global__ __launch_bounds__(256) void k_bn(const float* __restrict__ oraw,
                                            const float* __restrict__ part,
                                            const float* __restrict__ gamma,
                                            const float* __restrict__ beta,
                                            float* __restrict__ out) {
  __shared__ float mv[8], iv[8], bv[8];
  int tid = threadIdx.x;
  if (tid < 16) {
    int cc = tid >> 1, qq = tid & 1;
    float s = 0.f;
#pragma unroll
    for (int k = 0; k < ABLK; ++k) s += part[k * 16 + cc * 2 + qq];
    float other = __shfl_xor(s, 1);
    if (qq == 0) {
      float mean = s * (1.0f / 256.0f);
      float var  = other * (1.0f / 256.0f) - mean * mean;
      mv[cc] = mean;
      iv[cc] = gamma[cc] * rsqrtf(var + 1e-5f);
      bv[cc] = beta[cc];
    }
  }
  __syncthreads();
  for (int i = tid; i < BB * CC * 2; i += 256) {
    int c = (i >> 1) & 7;
    out[i] = (oraw[i] - mv[c]) * iv[c] + bv[c];
  }
}

// ---------------------------------------------------------------------------
extern "C" void kernel_launch(void* const* d_in, const int* in_sizes, int n_in,
                              void* d_out, int out_size, void* d_ws, size_t ws_size,
                              hipStream_t stream) {
  const float* x   = (const float*)d_in[0];
  const float* wr  = (const float*)d_in[1];
  const float* wi  = (const float*)d_in[2];
  const float* wc  = (const float*)d_in[3];
  const float* wor = (const float*)d_in[4];
  const float* woi = (const float*)d_in[5];
  const float* gm  = (const float*)d_in[6];
  const float* bt  = (const float*)d_in[7];
  float* out = (float*)d_out;

  float* ws     = (float*)d_ws;
  float* fpart2 = ws;                                   // 160*BB*NTILES = 655360 f32
  float* oraw   = fpart2 + (size_t)160 * BB * NTILES;   // 2048 f32
  float* part   = oraw + BB * CC * 2;                   // ABLK*16 = 1024 f32

  k_fir<<<dim3(BTILES * NTILES), dim3(512), 0, stream>>>(x, wr, wi, fpart2);
  k_nonlin<<<dim3(ABLK), dim3(256), 0, stream>>>(fpart2, wc, wor, woi, oraw, part);
  k_bn<<<dim3(1), dim3(256), 0, stream>>>(oraw, part, gm, bt, out);
}

// Round 12
// 48.811 us; speedup vs baseline: 1.7130x; 1.7130x over previous
//
#include <hip/hip_runtime.h>

#define BB 128
#define NN 16384
#define CC 8
#define WW 10
#define LL 16375            // N - W + 1
#define NT 512              // n's per block tile
#define NTILES (NN / NT)    // 32
#define BT 8                // b's per k_fir block (one wave per b)
#define BTILES (BB / BT)    // 16
#define WSL (NT + 9)        // 521 staged taps
#define SWSZ (WSL * 4 + 17) // f4 slots incl. skew padding
#define BPB 2               // b per k_nonlin block
#define ABLK (BB / BPB)     // 64

typedef float f4_t __attribute__((ext_vector_type(4)));

// ---------------------------------------------------------------------------
// K1: FIR. Grid = BTILES*NTILES = 512 blocks x 512 threads (8 waves).
// Wave wvb owns batch b = bt*8+wvb; lane = (c2, s), s = 16 slices x 32 n.
// Taps staged once per block in LDS (+(j>>5) skew). 16-slot register window.
// In-wave shfl reduce; lanes 0..39 store transposed to fpart2[r][b][nt].
// R11 bug fixed here: the epilogue selected acc[lane>>2] with a RUNTIME index,
// which forced the entire acc[10] f4 array into scratch (rule: runtime-indexed
// ext_vector arrays -> local memory). VGPR showed 64, WRITE_SIZE 163 MB of
// scratch spills, 100 us. Fix: compile-time unrolled predicated select.
// ---------------------------------------------------------------------------
__global__ __launch_bounds__(512, 2) void k_fir(const float* __restrict__ x,
                                                const float* __restrict__ wr,
                                                const float* __restrict__ wi,
                                                float* __restrict__ fpart2) {
  __shared__ f4_t sw[SWSZ];          // 33.6 KB
  int nt = blockIdx.x & (NTILES - 1);
  int bt = blockIdx.x >> 5;          // NTILES = 32
  int tid = threadIdx.x;
  int ntile = nt * NT;
  int l0 = ntile - 9;

  // ---- stage taps: sw[j*4 + c2 + (j>>5)] = {wr[2c2][l], wi[2c2][l], wr[2c2+1][l], wi[2c2+1][l]} ----
  {
    int c2s = tid & 3;
    int ca = 2 * c2s, cb = ca + 1;
    for (int j = tid >> 2; j < WSL; j += 128) {
      int l = l0 + j;
      f4_t v = (f4_t)0.f;
      if (l >= 0 && l < LL) {
        v[0] = wr[(size_t)ca * LL + l];
        v[1] = wi[(size_t)ca * LL + l];
        v[2] = wr[(size_t)cb * LL + l];
        v[3] = wi[(size_t)cb * LL + l];
      }
      sw[j * 4 + c2s + (j >> 5)] = v;
    }
  }
  __syncthreads();

  int wvb = tid >> 6;                // wave id = batch sub-index
  int b   = bt * BT + wvb;
  int c2  = tid & 3;
  int s   = (tid >> 2) & 15;         // 32-n slice
  int jbase = s * 32 + 9;            // tap j for local offset q: j = jbase + q

  const f4_t* __restrict__ xp = (const f4_t*)x + ((size_t)b * NN + ntile + s * 32) * 4 + c2;

#define TAP(q) sw[(jbase + (q)) * 4 + c2 + ((jbase + (q)) >> 5)]

  f4_t acc[WW];
#pragma unroll
  for (int w = 0; w < WW; ++w) acc[w] = (f4_t)0.f;

  f4_t wv[16];
  // preload slots 7..15 = taps q = -9..-1 (zero-padded in LDS)
#pragma unroll
  for (int k = 0; k < 9; ++k) wv[7 + k] = TAP(k - 9);

#pragma unroll
  for (int g = 0; g < 2; ++g) {
#pragma unroll
    for (int j = 0; j < 7; ++j) wv[j] = TAP(16 * g + j);
#pragma unroll
    for (int u = 0; u < 16; ++u) {
      f4_t xv = xp[(size_t)(16 * g + u) * 4];
#pragma unroll
      for (int w = 0; w < WW; ++w) {
        f4_t wt = wv[(u - w + 16) & 15];
        acc[w] += xv * wt;             // v_pk_fma_f32 x2
      }
      if (u <= 8) wv[u + 7] = TAP(16 * g + u + 7);   // refill after last use
    }
  }

  // ---- reduce over s (lane bits 2..5) fully in-wave ----
#pragma unroll
  for (int w = 0; w < WW; ++w)
#pragma unroll
    for (int e = 0; e < 4; ++e) {
      acc[w][e] += __shfl_xor(acc[w][e], 4);
      acc[w][e] += __shfl_xor(acc[w][e], 8);
      acc[w][e] += __shfl_xor(acc[w][e], 16);
      acc[w][e] += __shfl_xor(acc[w][e], 32);
    }

  // ---- store transposed: fpart2[(r*BB + b)*NTILES + nt], r = w*16 + c2*4 + e ----
  // Static-index select of this lane's acc row (NO runtime indexing of acc).
  int lane = tid & 63;
  if (lane < 40) {
    int wsel = lane >> 2;              // c2 = lane & 3 (matches compute c2)
    f4_t myacc = (f4_t)0.f;
#pragma unroll
    for (int w = 0; w < WW; ++w)
      if (w == wsel) myacc = acc[w];   // exec-masked moves, indices compile-time
#pragma unroll
    for (int e = 0; e < 4; ++e)
      fpart2[((size_t)(wsel * 16 + c2 * 4 + e) * BB + b) * NTILES + nt] = myacc[e];
  }
}

// ---------------------------------------------------------------------------
// K2: nonlin + projection. Grid = 64 blocks x 256 threads. Dense gather:
// thread-iter (r, bl) reads 8 consecutive float4 of fpart2 and tile-reduces.
// ---------------------------------------------------------------------------
__global__ __launch_bounds__(256) void k_nonlin(const float* __restrict__ fpart2,
                                                const float* __restrict__ wc,
                                                const float* __restrict__ wor,
                                                const float* __restrict__ woi,
                                                float* __restrict__ oraw,
                                                float* __restrict__ part) {
  __shared__ float sred[BPB][164];
  __shared__ float swc[672];
  __shared__ float swout[160];       // [p][c][w]

  int tid = threadIdx.x;
  int blk = blockIdx.x;
  int b0 = blk * BPB;

  for (int i = tid; i < 672; i += 256) swc[i] = wc[i];
  if (tid < 80) swout[tid] = wor[tid];
  else if (tid < 160) swout[tid] = woi[tid - 80];

  // dense stage: r = row (0..159), bl = batch-in-block; 8 consecutive f4 each
  for (int t = tid; t < 2 * 160; t += 256) {
    int r = t >> 1, bl = t & 1;
    const f4_t* fp = (const f4_t*)(fpart2 + ((size_t)r * BB + b0 + bl) * NTILES);
    f4_t s4 = (f4_t)0.f;
#pragma unroll
    for (int k = 0; k < NTILES / 4; ++k) s4 += fp[k];
    sred[bl][r] = s4[0] + s4[1] + s4[2] + s4[3];
  }
  __syncthreads();

  if (tid < 32) {
    int bl = tid >> 4;
    int c  = (tid >> 1) & 7;
    int p  = tid & 1;

    float wreg[8][2][3];
#pragma unroll
    for (int j = 0; j < 8; ++j) {
      int jj = j - (j > c ? 1 : 0);
      if (j == c) jj = 0;
#pragma unroll
      for (int ri = 0; ri < 2; ++ri)
#pragma unroll
        for (int d = 0; d < 3; ++d) {
          float v = swc[(c * 2 + p) * 42 + ri * 21 + jj * 3 + d];
          wreg[j][ri][d] = (j == c) ? 0.f : v;
        }
    }

    float o = 0.f;
    const float* wop = swout + p * 80 + c * 10;
#pragma unroll
    for (int w = 0; w < WW; ++w) {
      float4 f0 = *(const float4*)&sred[bl][w * 16];
      float4 f1 = *(const float4*)&sred[bl][w * 16 + 4];
      float4 f2 = *(const float4*)&sred[bl][w * 16 + 8];
      float4 f3 = *(const float4*)&sred[bl][w * 16 + 12];
      float fv[16] = {f0.x, f0.y, f0.z, f0.w, f1.x, f1.y, f1.z, f1.w,
                      f2.x, f2.y, f2.z, f2.w, f3.x, f3.y, f3.z, f3.w};
      float nl0 = 0.f, nl1 = 0.f, nl2 = 0.f;
#pragma unroll
      for (int j = 0; j < 8; ++j) {
        float r  = fv[2 * j];
        float im = fv[2 * j + 1];
        float r2 = r * r, i2 = im * im;
        float pw0 = r + im;
        float pw1 = r2 + i2;
        float pw2 = r2 * r + i2 * im;
        nl0 += (pw0 * r) * wreg[j][0][0] + (pw0 * im) * wreg[j][1][0];
        nl1 += (pw1 * r) * wreg[j][0][1] + (pw1 * im) * wreg[j][1][1];
        nl2 += (pw2 * r) * wreg[j][0][2] + (pw2 * im) * wreg[j][1][2];
      }
      o += (nl0 + nl1 + nl2) * wop[w];
    }

    oraw[((size_t)(b0 + bl) * CC + c) * 2 + p] = o;

    float s = o, q = o * o;
    s += __shfl_xor(s, 1);  q += __shfl_xor(q, 1);
    s += __shfl_xor(s, 16); q += __shfl_xor(q, 16);
    if ((tid & 17) == 0) {             // p==0 && bl==0 -> tid = c*2
      part[blk * 16 + c * 2 + 0] = s;
      part[blk * 16 + c * 2 + 1] = q;
    }
  }
}

// ---------------------------------------------------------------------------
// K3: BatchNorm finalize. 1 block x 256 threads.
// ---------------------------------------------------------------------------
__global__ __launch_bounds__(256) void k_bn(const float* __restrict__ oraw,
                                            const float* __restrict__ part,
                                            const float* __restrict__ gamma,
                                            const float* __restrict__ beta,
                                            float* __restrict__ out) {
  __shared__ float mv[8], iv[8], bv[8];
  int tid = threadIdx.x;
  if (tid < 16) {
    int cc = tid >> 1, qq = tid & 1;
    float s = 0.f;
#pragma unroll
    for (int k = 0; k < ABLK; ++k) s += part[k * 16 + cc * 2 + qq];
    float other = __shfl_xor(s, 1);
    if (qq == 0) {
      float mean = s * (1.0f / 256.0f);
      float var  = other * (1.0f / 256.0f) - mean * mean;
      mv[cc] = mean;
      iv[cc] = gamma[cc] * rsqrtf(var + 1e-5f);
      bv[cc] = beta[cc];
    }
  }
  __syncthreads();
  for (int i = tid; i < BB * CC * 2; i += 256) {
    int c = (i >> 1) & 7;
    out[i] = (oraw[i] - mv[c]) * iv[c] + bv[c];
  }
}

// ---------------------------------------------------------------------------
extern "C" void kernel_launch(void* const* d_in, const int* in_sizes, int n_in,
                              void* d_out, int out_size, void* d_ws, size_t ws_size,
                              hipStream_t stream) {
  const float* x   = (const float*)d_in[0];
  const float* wr  = (const float*)d_in[1];
  const float* wi  = (const float*)d_in[2];
  const float* wc  = (const float*)d_in[3];
  const float* wor = (const float*)d_in[4];
  const float* woi = (const float*)d_in[5];
  const float* gm  = (const float*)d_in[6];
  const float* bt  = (const float*)d_in[7];
  float* out = (float*)d_out;

  float* ws     = (float*)d_ws;
  float* fpart2 = ws;                                   // 160*BB*NTILES = 655360 f32
  float* oraw   = fpart2 + (size_t)160 * BB * NTILES;   // 2048 f32
  float* part   = oraw + BB * CC * 2;                   // ABLK*16 = 1024 f32

  k_fir<<<dim3(BTILES * NTILES), dim3(512), 0, stream>>>(x, wr, wi, fpart2);
  k_nonlin<<<dim3(ABLK), dim3(256), 0, stream>>>(fpart2, wc, wor, woi, oraw, part);
  k_bn<<<dim3(1), dim3(256), 0, stream>>>(oraw, part, gm, bt, out);
}

// Round 13
// 48.171 us; speedup vs baseline: 1.7357x; 1.0133x over previous
//
#include <hip/hip_runtime.h>

#define BB 128
#define NN 16384
#define CC 8
#define WW 10
#define LL 16375            // N - W + 1
#define NT 512              // n's per block tile
#define NTILES (NN / NT)    // 32
#define BT 8                // b's per k_fir block (one wave per b)
#define BTILES (BB / BT)    // 16
#define WSL (NT + 9)        // 521 staged taps
#define SWSZ (WSL * 4 + 4)  // f4 slots, [j][c2] linear
#define BPB 2               // b per k_nonlin block
#define ABLK (BB / BPB)     // 64

typedef float f4_t __attribute__((ext_vector_type(4)));

// ---------------------------------------------------------------------------
// K1: FIR with FULL-LINE x reads. Grid = 512 blocks x 512 threads (8 waves).
// Wave wvb owns batch b = bt*8+wvb. Lane = (c2, nlow, s): thread processes
// n = ntile + s*64 + 2u + nlow, u = 0..31 (stride-2 within a 64-n slice).
// For fixed u a wave-load covers 8 x 128B fully-consumed lines (the n-parity
// bit lives INSIDE the 8-lane line group) -> pure streaming, no L1 reliance.
// Taps in LDS [j][c2] f4 (no skew needed: (c2,nlow) spans all 8 bank groups).
// 16-slot window advances 2/step; slot schedule (2u+9-w)&15 is compile-time,
// per-lane offset jb = s*64+nlow lives in the address only (rule #20 safe).
// Epilogue identical to R12 (verified): shfl bits 2..5, transposed store.
// ---------------------------------------------------------------------------
__global__ __launch_bounds__(512, 2) void k_fir(const float* __restrict__ x,
                                                const float* __restrict__ wr,
                                                const float* __restrict__ wi,
                                                float* __restrict__ fpart2) {
  __shared__ f4_t sw[SWSZ];          // 33.4 KB, sw[j*4 + c2]
  int nt = blockIdx.x & (NTILES - 1);
  int bt = blockIdx.x >> 5;          // NTILES = 32
  int tid = threadIdx.x;
  int ntile = nt * NT;
  int l0 = ntile - 9;

  // ---- stage taps: sw[j*4 + c2s] = {wr[2c2][l], wi[2c2][l], wr[2c2+1][l], wi[2c2+1][l]} ----
  {
    int c2s = tid & 3;
    int ca = 2 * c2s, cb = ca + 1;
    for (int j = tid >> 2; j < WSL; j += 128) {
      int l = l0 + j;
      f4_t v = (f4_t)0.f;
      if (l >= 0 && l < LL) {
        v[0] = wr[(size_t)ca * LL + l];
        v[1] = wi[(size_t)ca * LL + l];
        v[2] = wr[(size_t)cb * LL + l];
        v[3] = wi[(size_t)cb * LL + l];
      }
      sw[j * 4 + c2s] = v;           // A = tid per round: conflict-free write
    }
  }
  __syncthreads();

  int wvb  = tid >> 6;               // wave id = batch sub-index
  int b    = bt * BT + wvb;
  int c2   = tid & 3;
  int nlow = (tid >> 2) & 1;         // n parity (inside the 128B line group)
  int s    = (tid >> 3) & 7;         // 64-n slice
  // per-lane tap base: j = jb + q, q = 2u+9-w in [2u, 2u+9]
  const f4_t* p = sw + (size_t)((s * 64 + nlow) * 4 + c2);

  const f4_t* __restrict__ xp =
      (const f4_t*)x + ((size_t)b * NN + ntile + s * 64 + nlow) * 4 + c2;

  f4_t acc[WW];
#pragma unroll
  for (int w = 0; w < WW; ++w) acc[w] = (f4_t)0.f;

  f4_t wv[16];
  // preload q = 0..9 into slots 0..9 (j = jb..jb+9; l0 zero-padding covers l<0)
#pragma unroll
  for (int q = 0; q < 10; ++q) wv[q] = p[q * 4];

#pragma unroll
  for (int u = 0; u < 32; ++u) {
    if (u >= 1) {                    // load q = 2u+8, 2u+9 (slots compile-time)
      wv[(2 * u + 8) & 15] = p[(2 * u + 8) * 4];
      wv[(2 * u + 9) & 15] = p[(2 * u + 9) * 4];
    }
    f4_t xv = xp[(size_t)u * 8];     // n = base + 2u : 8 full 128B lines/wave
#pragma unroll
    for (int w = 0; w < WW; ++w) {
      acc[w] += xv * wv[(2 * u + 9 - w) & 15];   // v_pk_fma_f32 x2
    }
  }

  // ---- reduce over nlow+s (lane bits 2..5) fully in-wave ----
#pragma unroll
  for (int w = 0; w < WW; ++w)
#pragma unroll
    for (int e = 0; e < 4; ++e) {
      acc[w][e] += __shfl_xor(acc[w][e], 4);
      acc[w][e] += __shfl_xor(acc[w][e], 8);
      acc[w][e] += __shfl_xor(acc[w][e], 16);
      acc[w][e] += __shfl_xor(acc[w][e], 32);
    }

  // ---- store transposed: fpart2[(r*BB + b)*NTILES + nt], r = w*16 + c2*4 + e ----
  // Static-index select of this lane's acc row (NO runtime indexing of acc).
  int lane = tid & 63;
  if (lane < 40) {
    int wsel = lane >> 2;            // c2 = lane & 3 (matches compute c2)
    f4_t myacc = (f4_t)0.f;
#pragma unroll
    for (int w = 0; w < WW; ++w)
      if (w == wsel) myacc = acc[w]; // exec-masked moves, indices compile-time
#pragma unroll
    for (int e = 0; e < 4; ++e)
      fpart2[((size_t)(wsel * 16 + c2 * 4 + e) * BB + b) * NTILES + nt] = myacc[e];
  }
}

// ---------------------------------------------------------------------------
// K2: nonlin + projection. Grid = 64 blocks x 256 threads. Dense gather:
// thread-iter (r, bl) reads 8 consecutive float4 of fpart2 and tile-reduces.
// ---------------------------------------------------------------------------
__global__ __launch_bounds__(256) void k_nonlin(const float* __restrict__ fpart2,
                                                const float* __restrict__ wc,
                                                const float* __restrict__ wor,
                                                const float* __restrict__ woi,
                                                float* __restrict__ oraw,
                                                float* __restrict__ part) {
  __shared__ float sred[BPB][164];
  __shared__ float swc[672];
  __shared__ float swout[160];       // [p][c][w]

  int tid = threadIdx.x;
  int blk = blockIdx.x;
  int b0 = blk * BPB;

  for (int i = tid; i < 672; i += 256) swc[i] = wc[i];
  if (tid < 80) swout[tid] = wor[tid];
  else if (tid < 160) swout[tid] = woi[tid - 80];

  // dense stage: r = row (0..159), bl = batch-in-block; 8 consecutive f4 each
  for (int t = tid; t < 2 * 160; t += 256) {
    int r = t >> 1, bl = t & 1;
    const f4_t* fp = (const f4_t*)(fpart2 + ((size_t)r * BB + b0 + bl) * NTILES);
    f4_t s4 = (f4_t)0.f;
#pragma unroll
    for (int k = 0; k < NTILES / 4; ++k) s4 += fp[k];
    sred[bl][r] = s4[0] + s4[1] + s4[2] + s4[3];
  }
  __syncthreads();

  if (tid < 32) {
    int bl = tid >> 4;
    int c  = (tid >> 1) & 7;
    int p  = tid & 1;

    float wreg[8][2][3];
#pragma unroll
    for (int j = 0; j < 8; ++j) {
      int jj = j - (j > c ? 1 : 0);
      if (j == c) jj = 0;
#pragma unroll
      for (int ri = 0; ri < 2; ++ri)
#pragma unroll
        for (int d = 0; d < 3; ++d) {
          float v = swc[(c * 2 + p) * 42 + ri * 21 + jj * 3 + d];
          wreg[j][ri][d] = (j == c) ? 0.f : v;
        }
    }

    float o = 0.f;
    const float* wop = swout + p * 80 + c * 10;
#pragma unroll
    for (int w = 0; w < WW; ++w) {
      float4 f0 = *(const float4*)&sred[bl][w * 16];
      float4 f1 = *(const float4*)&sred[bl][w * 16 + 4];
      float4 f2 = *(const float4*)&sred[bl][w * 16 + 8];
      float4 f3 = *(const float4*)&sred[bl][w * 16 + 12];
      float fv[16] = {f0.x, f0.y, f0.z, f0.w, f1.x, f1.y, f1.z, f1.w,
                      f2.x, f2.y, f2.z, f2.w, f3.x, f3.y, f3.z, f3.w};
      float nl0 = 0.f, nl1 = 0.f, nl2 = 0.f;
#pragma unroll
      for (int j = 0; j < 8; ++j) {
        float r  = fv[2 * j];
        float im = fv[2 * j + 1];
        float r2 = r * r, i2 = im * im;
        float pw0 = r + im;
        float pw1 = r2 + i2;
        float pw2 = r2 * r + i2 * im;
        nl0 += (pw0 * r) * wreg[j][0][0] + (pw0 * im) * wreg[j][1][0];
        nl1 += (pw1 * r) * wreg[j][0][1] + (pw1 * im) * wreg[j][1][1];
        nl2 += (pw2 * r) * wreg[j][0][2] + (pw2 * im) * wreg[j][1][2];
      }
      o += (nl0 + nl1 + nl2) * wop[w];
    }

    oraw[((size_t)(b0 + bl) * CC + c) * 2 + p] = o;

    float s = o, q = o * o;
    s += __shfl_xor(s, 1);  q += __shfl_xor(q, 1);
    s += __shfl_xor(s, 16); q += __shfl_xor(q, 16);
    if ((tid & 17) == 0) {             // p==0 && bl==0 -> tid = c*2
      part[blk * 16 + c * 2 + 0] = s;
      part[blk * 16 + c * 2 + 1] = q;
    }
  }
}

// ---------------------------------------------------------------------------
// K3: BatchNorm finalize. 1 block x 256 threads.
// ---------------------------------------------------------------------------
__global__ __launch_bounds__(256) void k_bn(const float* __restrict__ oraw,
                                            const float* __restrict__ part,
                                            const float* __restrict__ gamma,
                                            const float* __restrict__ beta,
                                            float* __restrict__ out) {
  __shared__ float mv[8], iv[8], bv[8];
  int tid = threadIdx.x;
  if (tid < 16) {
    int cc = tid >> 1, qq = tid & 1;
    float s = 0.f;
#pragma unroll
    for (int k = 0; k < ABLK; ++k) s += part[k * 16 + cc * 2 + qq];
    float other = __shfl_xor(s, 1);
    if (qq == 0) {
      float mean = s * (1.0f / 256.0f);
      float var  = other * (1.0f / 256.0f) - mean * mean;
      mv[cc] = mean;
      iv[cc] = gamma[cc] * rsqrtf(var + 1e-5f);
      bv[cc] = beta[cc];
    }
  }
  __syncthreads();
  for (int i = tid; i < BB * CC * 2; i += 256) {
    int c = (i >> 1) & 7;
    out[i] = (oraw[i] - mv[c]) * iv[c] + bv[c];
  }
}

// ---------------------------------------------------------------------------
extern "C" void kernel_launch(void* const* d_in, const int* in_sizes, int n_in,
                              void* d_out, int out_size, void* d_ws, size_t ws_size,
                              hipStream_t stream) {
  const float* x   = (const float*)d_in[0];
  const float* wr  = (const float*)d_in[1];
  const float* wi  = (const float*)d_in[2];
  const float* wc  = (const float*)d_in[3];
  const float* wor = (const float*)d_in[4];
  const float* woi = (const float*)d_in[5];
  const float* gm  = (const float*)d_in[6];
  const float* bt  = (const float*)d_in[7];
  float* out = (float*)d_out;

  float* ws     = (float*)d_ws;
  float* fpart2 = ws;                                   // 160*BB*NTILES = 655360 f32
  float* oraw   = fpart2 + (size_t)160 * BB * NTILES;   // 2048 f32
  float* part   = oraw + BB * CC * 2;                   // ABLK*16 = 1024 f32

  k_fir<<<dim3(BTILES * NTILES), dim3(512), 0, stream>>>(x, wr, wi, fpart2);
  k_nonlin<<<dim3(ABLK), dim3(256), 0, stream>>>(fpart2, wc, wor, woi, oraw, part);
  k_bn<<<dim3(1), dim3(256), 0, stream>>>(oraw, part, gm, bt, out);
}